// Round 16
// baseline (118.391 us; speedup 1.0000x reference)
//
#include <hip/hip_runtime.h>
#include <hip/hip_bf16.h>
#include <math.h>

#define BB 8
#define TT 4096
#define HD 64

typedef __attribute__((ext_vector_type(8))) short short8;
typedef __attribute__((ext_vector_type(4))) float f32x4;
typedef __attribute__((ext_vector_type(16))) float f32x16;
typedef __attribute__((ext_vector_type(2))) unsigned int uint2v;
typedef __attribute__((ext_vector_type(4))) unsigned int uint4v;

#define LOG2E 1.44269504088896f

// 1-inst packed f32->bf16 (RNE). src0 -> lo, src1 -> hi.
__device__ __forceinline__ unsigned pack_bf2(float a, float b) {
    unsigned r;
    asm("v_cvt_pk_bf16_f32 %0, %1, %2" : "=v"(r) : "v"(a), "v"(b));
    return r;
}
__device__ __forceinline__ unsigned short bfbits(float f) {
    unsigned r;
    asm("v_cvt_pk_bf16_f32 %0, %1, %2" : "=v"(r) : "v"(f), "v"(f));
    return (unsigned short)r;
}
__device__ __forceinline__ float bf2f(unsigned short u) {
    unsigned v = (unsigned)u << 16;
    return __builtin_bit_cast(float, v);
}
__device__ __forceinline__ float fexp2(float x) {     // raw v_exp_f32
    return __builtin_amdgcn_exp2f(x);
}
__device__ __forceinline__ short8 cvt8(float4 a, float4 b, float sc) {
    uint4v u;
    u[0] = pack_bf2(a.x * sc, a.y * sc);
    u[1] = pack_bf2(a.z * sc, a.w * sc);
    u[2] = pack_bf2(b.x * sc, b.y * sc);
    u[3] = pack_bf2(b.z * sc, b.w * sc);
    return __builtin_bit_cast(short8, u);
}

// ---------------- Kernel 1: MFMA QKV projection (R13, proven) ----------------
__global__ __launch_bounds__(256) void qkv_proj_mfma(
    const float* __restrict__ x,
    const float* __restrict__ Wk, const float* __restrict__ Wq, const float* __restrict__ Wv,
    unsigned short* __restrict__ qo, unsigned short* __restrict__ ko,
    unsigned short* __restrict__ vto)
{
    __shared__ short lds[26112];          // 52 KB
    short* xls = lds;
    short* wls = lds + 8192;

    const int tid = threadIdx.x;
    const int l = tid & 63, w = tid >> 6;
    const int hi = l >> 5, c31 = l & 31;
    const long t0 = (long)blockIdx.x * 128;
    const int b = (int)(t0 >> 12);
    const int tl0 = (int)(t0 & 4095);

#pragma unroll
    for (int i = 0; i < 4; ++i) {
        int slot = tid + 256 * i;
        int row = slot >> 3, bl = slot & 7;
        const float* xp = x + (t0 + row) * 64 + 8 * bl;
        float4 a = *(const float4*)xp;
        float4 bq = *(const float4*)(xp + 4);
        *(short8*)&xls[row * 64 + 8 * (bl ^ (row & 7))] = cvt8(a, bq, 1.f);
    }
#pragma unroll
    for (int i = 0; i < 6; ++i) {
        int slot = tid + 256 * i;
        int row = slot >> 3, bl = slot & 7;
        const float* wp;
        float sc;
        if (row < 64)       { wp = Wq + row * 64;         sc = 0.125f * LOG2E; }
        else if (row < 128) { wp = Wk + (row - 64) * 64;  sc = 1.f; }
        else                { wp = Wv + (row - 128) * 64; sc = 1.f; }
        wp += 8 * bl;
        float4 a = *(const float4*)wp;
        float4 bq = *(const float4*)(wp + 4);
        *(short8*)&wls[row * 64 + 8 * (bl ^ (row & 7))] = cvt8(a, bq, sc);
    }
    __syncthreads();

    short8 xf[4];
#pragma unroll
    for (int ki = 0; ki < 4; ++ki) {
        int row = 32 * w + c31;
        xf[ki] = *(const short8*)&xls[row * 64 + 8 * ((2 * ki + hi) ^ (row & 7))];
    }
    f32x16 cqk[4] = {};
#pragma unroll
    for (int nt = 0; nt < 4; ++nt) {
#pragma unroll
        for (int ki = 0; ki < 4; ++ki) {
            int row = 32 * nt + c31;
            short8 wf = *(const short8*)&wls[row * 64 + 8 * ((2 * ki + hi) ^ (row & 7))];
            cqk[nt] = __builtin_amdgcn_mfma_f32_32x32x16_bf16(xf[ki], wf, cqk[nt], 0, 0, 0);
        }
    }
    f32x16 cv[2] = {};
#pragma unroll
    for (int rt = 0; rt < 2; ++rt) {
#pragma unroll
        for (int ki = 0; ki < 4; ++ki) {
            int row = 128 + 32 * rt + c31;
            short8 wf = *(const short8*)&wls[row * 64 + 8 * ((2 * ki + hi) ^ (row & 7))];
            cv[rt] = __builtin_amdgcn_mfma_f32_32x32x16_bf16(wf, xf[ki], cv[rt], 0, 0, 0);
        }
    }

    __syncthreads();
    short* cb = lds;                      // 128 x 136 q,k bounce
    short* vb = lds + 17408;              // 64 x 136 v bounce
#pragma unroll
    for (int nt = 0; nt < 4; ++nt) {
#pragma unroll
        for (int r = 0; r < 16; ++r) {
            int trow = 32 * w + (r & 3) + 8 * (r >> 2) + 4 * hi;
            cb[trow * 136 + 32 * nt + c31] = (short)bfbits(cqk[nt][r]);
        }
    }
#pragma unroll
    for (int rt = 0; rt < 2; ++rt) {
#pragma unroll
        for (int r = 0; r < 16; ++r) {
            int h = 32 * rt + (r & 3) + 8 * (r >> 2) + 4 * hi;
            vb[h * 136 + 32 * w + c31] = (short)bfbits(cv[rt][r]);
        }
    }
    __syncthreads();
    {
        int row = tid >> 1, seg = tid & 1;
        const short8* cp = (const short8*)&cb[row * 136 + seg * 64];
        unsigned short* dst = (seg == 0 ? qo : ko) + (t0 + row) * 64;
#pragma unroll
        for (int i = 0; i < 8; ++i) ((short8*)dst)[i] = cp[i];
    }
#pragma unroll
    for (int i = 0; i < 4; ++i) {
        int slot = tid + 256 * i;
        int h = slot >> 4, tc = slot & 15;
        short8 vv = *(const short8*)&vb[h * 136 + 8 * tc];
        *(short8*)(vto + ((long)b * 64 + h) * 4096 + tl0 + 8 * tc) = vv;
    }
}

// ---------------- Kernel 2: MFMA flash attention — 8-wave block, shared KV tile ----------------
// 512 thr = 8 waves x 32 q-rows (block = 256 q-rows). One 64-wide K + V^T tile
// shared by all 8 waves: 1 K-load + 1 V-load per thread per tile (staging cost
// per wave-tile halved vs 4-wave). 3-buffer counted-vmcnt (T3/T4), 48 KB LDS ->
// 3 blocks/CU = 24 waves/CU. Per-wave compute identical to proven R14 path.
__global__ __launch_bounds__(512, 6) void attn_mfma(
    const unsigned short* __restrict__ qg,
    const unsigned short* __restrict__ kg,
    const unsigned short* __restrict__ vtg,
    unsigned short* __restrict__ Opart,
    float2* __restrict__ ml,
    float* __restrict__ outg,
    int sh, int CPB)
{
    __shared__ short kls[3][4096];
    __shared__ short vls[3][4096];

    const int CT = 1 << sh;                    // chunk length in 64-wide tiles
    const int tid = threadIdx.x;
    const int l = tid & 63, w = tid >> 6;      // w in {0..7}
    const int q = l & 31, hi = l >> 5;
    const int qs7 = q & 7;

    const int bid = blockIdx.x;
    const int b = bid & 7;
    const int j = bid >> 3;
    int qt = 0, ci = 0;                        // qt in 0..15 (256-row q-blocks)
    {
        int acc = 0;
        for (int qq = 15; qq >= 0; --qq) {     // descending size (LPT)
            int nc = (4 * qq + 3 + CT) >> sh;  // ceil((4qq+4)/CT)
            if (j < acc + nc) { qt = qq; ci = j - acc; break; }
            acc += nc;
        }
    }
    const int nch = (4 * qt + 3 + CT) >> sh;
    int ntile = 4 * qt + 4 - CT * ci;
    if (ntile > CT) ntile = CT;
    const int c0 = (ci * CT) << 6;

    const int q0w = qt * 256 + 32 * w;
    const int qr = q0w + q;
    const int lastg = (q0w + 31) >> 6;         // = 4qt + (w>>1)

    const unsigned short* qb = qg + ((long)b * TT + qr) * HD;
    short8 qf[4];
#pragma unroll
    for (int ki = 0; ki < 4; ++ki) qf[ki] = *(const short8*)(qb + 16 * ki + 8 * hi);

    int ofs[2][4];                             // LDS fragment byte offsets (K and V^T)
#pragma unroll
    for (int a = 0; a < 2; ++a)
#pragma unroll
        for (int i2 = 0; i2 < 4; ++i2)
            ofs[a][i2] = (32 * a + q) * 128 + 16 * ((2 * i2 + hi) ^ qs7);

    f32x16 oacc[2] = {};
    float m = -INFINITY, lsum = 0.f;           // lsum: own-half partial

    const unsigned short* kbase = kg + (long)b * TT * HD;
    const unsigned short* vbase = vtg + (long)b * HD * TT;

    // staging: thread -> (row = tid>>3 in 0..63, bl = tid&7); source pre-swizzled.
    const int r8 = l >> 3;                     // row = 8w + r8
    const int blsw = (l & 7) ^ r8;             // (row&7) == r8 since row = 8w + r8
    const long koff0 = (long)(8 * w + r8) * HD + 8 * blsw;
    const long voff0 = (long)(8 * w + r8) * TT + 8 * blsw;

#define STAGE(buf_, s_) do {                                                            \
    const unsigned short* kp_ = kbase + (long)(s_) * HD + koff0;                        \
    const unsigned short* vp_ = vbase + (s_) + voff0;                                   \
    short* kd_ = &kls[buf_][512 * w];                                                   \
    short* vd_ = &vls[buf_][512 * w];                                                   \
    __builtin_amdgcn_global_load_lds((const __attribute__((address_space(1))) void*)kp_, \
                                     (__attribute__((address_space(3))) void*)kd_, 16, 0, 0); \
    __builtin_amdgcn_global_load_lds((const __attribute__((address_space(1))) void*)vp_, \
                                     (__attribute__((address_space(3))) void*)vd_, 16, 0, 0); \
} while (0)

    STAGE(0, c0);
    if (ntile > 1) STAGE(1, c0 + 64);

    int cur = 0, nxt2 = 2;
    for (int it = 0; it < ntile; ++it) {
        const int s0 = c0 + (it << 6);
        // counted drain: tile it's 2 loads done; tile it+1's 2 may stay in flight.
        if (it + 1 < ntile) asm volatile("s_waitcnt vmcnt(2)" ::: "memory");
        else                asm volatile("s_waitcnt vmcnt(0)" ::: "memory");
        __builtin_amdgcn_s_barrier();
        __builtin_amdgcn_sched_barrier(0);
        if (it + 2 < ntile) STAGE(nxt2, s0 + 128);

        if (s0 <= q0w + 31) {
            const int gti = ci * CT + it;
            const int nkt = (gti == lastg && (w & 1) == 0) ? 1 : 2;
            const short* kb_ = kls[cur];
            const short* vb_ = vls[cur];

            // ---- S^T = K Q^T ----
            f32x16 sacc[2] = {};
            __builtin_amdgcn_s_setprio(1);
#pragma unroll
            for (int kt = 0; kt < 2; ++kt) {
                if (kt < nkt) {
#pragma unroll
                    for (int ki = 0; ki < 4; ++ki) {
                        short8 kf = *(const short8*)((const char*)kb_ + ofs[kt][ki]);
                        sacc[kt] = __builtin_amdgcn_mfma_f32_32x32x16_bf16(kf, qf[ki], sacc[kt], 0, 0, 0);
                    }
                }
            }
            __builtin_amdgcn_s_setprio(0);

            // ---- causal mask (diag tile only) ----
            if (gti == lastg) {
#pragma unroll
                for (int kt = 0; kt < 2; ++kt) {
                    if (kt >= nkt) continue;
#pragma unroll
                    for (int r = 0; r < 16; ++r) {
                        int kkg = s0 + 32 * kt + (r & 3) + 8 * (r >> 2) + 4 * hi;
                        if (kkg > qr) sacc[kt][r] = -INFINITY;
                    }
                }
            }

            // ---- lane-local tree max; rescale only beyond threshold (T13) ----
            float t8[8];
#pragma unroll
            for (int r = 0; r < 8; ++r) {
                float a = fmaxf(sacc[0][r], sacc[0][r + 8]);
                if (nkt == 2) a = fmaxf(a, fmaxf(sacc[1][r], sacc[1][r + 8]));
                t8[r] = a;
            }
            float pmax = fmaxf(fmaxf(fmaxf(t8[0], t8[1]), fmaxf(t8[2], t8[3])),
                               fmaxf(fmaxf(t8[4], t8[5]), fmaxf(t8[6], t8[7])));
            if (__any(pmax > m + 11.0f)) {     // rare in steady state
                pmax = fmaxf(pmax, __shfl_xor(pmax, 32, 64));
                float mn = fmaxf(m, pmax);
                float fac = fexp2(m - mn);
                lsum *= fac;
                oacc[0] *= fac;
                oacc[1] *= fac;
                m = mn;
            }

            // ---- P = exp2(S - m) via raw v_exp; pack via v_cvt_pk ----
            float rsum = 0.f;
            unsigned ulo[8], uhi[8];
#pragma unroll
            for (int kt = 0; kt < 2; ++kt) {
#pragma unroll
                for (int jj = 0; jj < 4; ++jj) {
                    if (kt < nkt) {
                        float p0 = fexp2(sacc[kt][4 * jj + 0] - m);
                        float p1 = fexp2(sacc[kt][4 * jj + 1] - m);
                        float p2 = fexp2(sacc[kt][4 * jj + 2] - m);
                        float p3 = fexp2(sacc[kt][4 * jj + 3] - m);
                        rsum += (p0 + p1) + (p2 + p3);
                        ulo[4 * kt + jj] = pack_bf2(p0, p1);
                        uhi[4 * kt + jj] = pack_bf2(p2, p3);
                    } else {
                        ulo[4 * kt + jj] = 0;
                        uhi[4 * kt + jj] = 0;
                    }
                }
            }
            lsum += rsum;                      // per-half; combined in epilogue

            // ---- O^T += V^T P (P -> A-frag via permlane32_swap) ----
            const int nks = 2 * nkt;
#pragma unroll
            for (int ks = 0; ks < 4; ++ks) {
                if (ks >= nks) continue;
                uint2v rlo = __builtin_amdgcn_permlane32_swap(ulo[2 * ks], ulo[2 * ks + 1], false, false);
                uint2v rhi = __builtin_amdgcn_permlane32_swap(uhi[2 * ks], uhi[2 * ks + 1], false, false);
                uint4v paw;
                paw[0] = rlo[0]; paw[1] = rhi[0]; paw[2] = rlo[1]; paw[3] = rhi[1];
                short8 pa = __builtin_bit_cast(short8, paw);
                __builtin_amdgcn_s_setprio(1);
#pragma unroll
                for (int dt = 0; dt < 2; ++dt) {
                    short8 vf = *(const short8*)((const char*)vb_ + ofs[dt][ks]);
                    oacc[dt] = __builtin_amdgcn_mfma_f32_32x32x16_bf16(vf, pa, oacc[dt], 0, 0, 0);
                }
                __builtin_amdgcn_s_setprio(0);
            }
        }
        cur = (cur == 2) ? 0 : cur + 1;
        nxt2 = (nxt2 == 2) ? 0 : nxt2 + 1;
    }
#undef STAGE

    lsum += __shfl_xor(lsum, 32, 64);          // combine per-half sums once

    const int lr = 32 * w + q;                 // 0..255 within block
    if (nch == 1) {
        const float inv = 1.f / lsum;
        float* op = outg + ((long)b * TT + qr) * HD;
#pragma unroll
        for (int dt = 0; dt < 2; ++dt) {
#pragma unroll
            for (int jj = 0; jj < 4; ++jj) {
                f32x4 o4;
                o4[0] = oacc[dt][4 * jj + 0] * inv;
                o4[1] = oacc[dt][4 * jj + 1] * inv;
                o4[2] = oacc[dt][4 * jj + 2] * inv;
                o4[3] = oacc[dt][4 * jj + 3] * inv;
                *(f32x4*)(op + 32 * dt + 8 * jj + 4 * hi) = o4;
            }
        }
    } else {
        const float inv = lsum > 0.f ? 1.f / lsum : 0.f;
        unsigned short* po = Opart + ((long)(b * CPB + j) * 256 + lr) * 64;
#pragma unroll
        for (int dt = 0; dt < 2; ++dt) {
#pragma unroll
            for (int jj = 0; jj < 4; ++jj) {
                uint2v u;
                u[0] = pack_bf2(oacc[dt][4 * jj + 0] * inv, oacc[dt][4 * jj + 1] * inv);
                u[1] = pack_bf2(oacc[dt][4 * jj + 2] * inv, oacc[dt][4 * jj + 3] * inv);
                *(uint2v*)(po + 32 * dt + 8 * jj + 4 * hi) = u;
            }
        }
        ml[(long)(b * CPB + j) * 256 + lr] = make_float2(m, lsum);
    }
}

// ---------------- Kernel 3: combine partials (256-row blocks; exp2 domain) ----------------
__global__ __launch_bounds__(512) void combine(
    const unsigned short* __restrict__ Opart,
    const float2* __restrict__ ml,
    float* __restrict__ outg,
    int sh, int qtmin, int CPB)
{
    const int CT = 1 << sh;
    const int bid = blockIdx.x;
    const int b = bid & 7, qt = qtmin + (bid >> 3);
    const int nc = (4 * qt + 3 + CT) >> sh;    // 2..16
    int jb = 0;
    for (int qq = 15; qq > qt; --qq) jb += (4 * qq + 3 + CT) >> sh;

    const int tid = threadIdx.x;
    const int row = tid >> 1, dh = (tid & 1) * 32;
    const long base = (long)(b * CPB + jb) * 256 + row;

    float mv[16], lv[16], M = -INFINITY;
#pragma unroll
    for (int c = 0; c < 16; ++c) {
        mv[c] = -INFINITY; lv[c] = 0.f;
        if (c < nc) {
            float2 t = ml[base + (long)c * 256];
            mv[c] = t.x; lv[c] = t.y;
            M = fmaxf(M, mv[c]);
        }
    }
    float L = 0.f, wt[16];
#pragma unroll
    for (int c = 0; c < 16; ++c) {
        wt[c] = (c < nc) ? lv[c] * fexp2(mv[c] - M) : 0.f;
        L += wt[c];
    }
    float acc[32];
#pragma unroll
    for (int i = 0; i < 32; ++i) acc[i] = 0.f;
#pragma unroll
    for (int c = 0; c < 16; ++c) {
        if (c < nc && wt[c] > 0.f) {
            const short8* op = (const short8*)(Opart + (base + (long)c * 256) * 64 + dh);
#pragma unroll
            for (int i = 0; i < 4; ++i) {
                short8 v = op[i];
#pragma unroll
                for (int e = 0; e < 8; ++e)
                    acc[8 * i + e] += wt[c] * bf2f((unsigned short)v[e]);
            }
        }
    }
    const float invL = 1.f / L;
    float* dst = outg + ((long)b * TT + qt * 256 + row) * HD + dh;
#pragma unroll
    for (int i = 0; i < 8; ++i) {
        f32x4 o;
        o[0] = acc[4 * i + 0] * invL; o[1] = acc[4 * i + 1] * invL;
        o[2] = acc[4 * i + 2] * invL; o[3] = acc[4 * i + 3] * invL;
        *(f32x4*)(dst + 4 * i) = o;
    }
}

extern "C" void kernel_launch(void* const* d_in, const int* in_sizes, int n_in,
                              void* d_out, int out_size, void* d_ws, size_t ws_size,
                              hipStream_t stream) {
    const float* x  = (const float*)d_in[0];
    const float* Wk = (const float*)d_in[1];
    const float* Wq = (const float*)d_in[2];
    const float* Wv = (const float*)d_in[3];
    float* out = (float*)d_out;

    const long N = (long)BB * TT * HD;
    unsigned short* q16 = (unsigned short*)d_ws;        // 4 MiB
    unsigned short* k16 = q16 + N;                      // 4 MiB
    unsigned short* vt16 = k16 + N;                     // 4 MiB (V^T [b][d][t])
    const size_t qkv_bytes = 12582912;

    // chunk selection: densest CT that fits ws (CPB = sum_qt ceil((4qt+4)/CT))
    // per-chunk partial bytes/batch-block-row: 256 rows x (64x2B O' + 8B ml) = 136B/row
    int sh = 4, CPB = 40;                               // CT=16 always fits (23.7 MB)
    {
        const size_t need4 = qkv_bytes + (size_t)136 * 8 * 256 * 136;  // 50.46 MB
        const size_t need8 = qkv_bytes + (size_t)72  * 8 * 256 * 136;  // 32.63 MB
        if (ws_size >= need4)      { sh = 2; CPB = 136; }
        else if (ws_size >= need8) { sh = 3; CPB = 72;  }
    }
    unsigned short* Opart = (unsigned short*)((char*)d_ws + qkv_bytes);
    float2* mlp = (float2*)((char*)d_ws + qkv_bytes + (size_t)CPB * 8 * 256 * 64 * 2);
    const int qtmin = 1 << (sh - 2);                    // first qt needing combine

    qkv_proj_mfma<<<BB * TT / 128, 256, 0, stream>>>(x, Wk, Wq, Wv, q16, k16, vt16);
    attn_mfma<<<8 * CPB, 512, 0, stream>>>(q16, k16, vt16, Opart, mlp, out, sh, CPB);
    combine<<<8 * (16 - qtmin), 512, 0, stream>>>(Opart, mlp, out, sh, qtmin, CPB);
}

// Round 19
// 60.635 us; speedup vs baseline: 1.9525x; 1.9525x over previous
//
#include <hip/hip_runtime.h>
#include <hip/hip_bf16.h>
#include <math.h>

#define BB 8
#define TT 4096
#define HD 64

typedef __attribute__((ext_vector_type(8))) short short8;
typedef __attribute__((ext_vector_type(4))) float f32x4;
typedef __attribute__((ext_vector_type(16))) float f32x16;
typedef __attribute__((ext_vector_type(2))) unsigned int uint2v;
typedef __attribute__((ext_vector_type(4))) unsigned int uint4v;

#define LOG2E 1.44269504088896f

// 1-inst packed f32->bf16 (RNE). src0 -> lo, src1 -> hi (matches a | b<<16).
__device__ __forceinline__ unsigned pack_bf2(float a, float b) {
    unsigned r;
    asm("v_cvt_pk_bf16_f32 %0, %1, %2" : "=v"(r) : "v"(a), "v"(b));
    return r;
}
__device__ __forceinline__ unsigned short bfbits(float f) {
    unsigned r;
    asm("v_cvt_pk_bf16_f32 %0, %1, %2" : "=v"(r) : "v"(f), "v"(f));
    return (unsigned short)r;
}
__device__ __forceinline__ float bf2f(unsigned short u) {
    unsigned v = (unsigned)u << 16;
    return __builtin_bit_cast(float, v);
}
__device__ __forceinline__ float fexp2(float x) {     // raw v_exp_f32
    return __builtin_amdgcn_exp2f(x);
}
__device__ __forceinline__ short8 cvt8(float4 a, float4 b, float sc) {
    uint4v u;
    u[0] = pack_bf2(a.x * sc, a.y * sc);
    u[1] = pack_bf2(a.z * sc, a.w * sc);
    u[2] = pack_bf2(b.x * sc, b.y * sc);
    u[3] = pack_bf2(b.z * sc, b.w * sc);
    return __builtin_bit_cast(short8, u);
}

// ---------------- Kernel 1: MFMA QKV projection (R13, proven) ----------------
__global__ __launch_bounds__(256) void qkv_proj_mfma(
    const float* __restrict__ x,
    const float* __restrict__ Wk, const float* __restrict__ Wq, const float* __restrict__ Wv,
    unsigned short* __restrict__ qo, unsigned short* __restrict__ ko,
    unsigned short* __restrict__ vto)
{
    __shared__ short lds[26112];          // 52 KB
    short* xls = lds;
    short* wls = lds + 8192;

    const int tid = threadIdx.x;
    const int l = tid & 63, w = tid >> 6;
    const int hi = l >> 5, c31 = l & 31;
    const long t0 = (long)blockIdx.x * 128;
    const int b = (int)(t0 >> 12);
    const int tl0 = (int)(t0 & 4095);

#pragma unroll
    for (int i = 0; i < 4; ++i) {
        int slot = tid + 256 * i;
        int row = slot >> 3, bl = slot & 7;
        const float* xp = x + (t0 + row) * 64 + 8 * bl;
        float4 a = *(const float4*)xp;
        float4 bq = *(const float4*)(xp + 4);
        *(short8*)&xls[row * 64 + 8 * (bl ^ (row & 7))] = cvt8(a, bq, 1.f);
    }
#pragma unroll
    for (int i = 0; i < 6; ++i) {
        int slot = tid + 256 * i;
        int row = slot >> 3, bl = slot & 7;
        const float* wp;
        float sc;
        if (row < 64)       { wp = Wq + row * 64;         sc = 0.125f * LOG2E; }
        else if (row < 128) { wp = Wk + (row - 64) * 64;  sc = 1.f; }
        else                { wp = Wv + (row - 128) * 64; sc = 1.f; }
        wp += 8 * bl;
        float4 a = *(const float4*)wp;
        float4 bq = *(const float4*)(wp + 4);
        *(short8*)&wls[row * 64 + 8 * (bl ^ (row & 7))] = cvt8(a, bq, sc);
    }
    __syncthreads();

    short8 xf[4];
#pragma unroll
    for (int ki = 0; ki < 4; ++ki) {
        int row = 32 * w + c31;
        xf[ki] = *(const short8*)&xls[row * 64 + 8 * ((2 * ki + hi) ^ (row & 7))];
    }
    f32x16 cqk[4] = {};
#pragma unroll
    for (int nt = 0; nt < 4; ++nt) {
#pragma unroll
        for (int ki = 0; ki < 4; ++ki) {
            int row = 32 * nt + c31;
            short8 wf = *(const short8*)&wls[row * 64 + 8 * ((2 * ki + hi) ^ (row & 7))];
            cqk[nt] = __builtin_amdgcn_mfma_f32_32x32x16_bf16(xf[ki], wf, cqk[nt], 0, 0, 0);
        }
    }
    f32x16 cv[2] = {};
#pragma unroll
    for (int rt = 0; rt < 2; ++rt) {
#pragma unroll
        for (int ki = 0; ki < 4; ++ki) {
            int row = 128 + 32 * rt + c31;
            short8 wf = *(const short8*)&wls[row * 64 + 8 * ((2 * ki + hi) ^ (row & 7))];
            cv[rt] = __builtin_amdgcn_mfma_f32_32x32x16_bf16(wf, xf[ki], cv[rt], 0, 0, 0);
        }
    }

    __syncthreads();
    short* cb = lds;                      // 128 x 136 q,k bounce
    short* vb = lds + 17408;              // 64 x 136 v bounce
#pragma unroll
    for (int nt = 0; nt < 4; ++nt) {
#pragma unroll
        for (int r = 0; r < 16; ++r) {
            int trow = 32 * w + (r & 3) + 8 * (r >> 2) + 4 * hi;
            cb[trow * 136 + 32 * nt + c31] = (short)bfbits(cqk[nt][r]);
        }
    }
#pragma unroll
    for (int rt = 0; rt < 2; ++rt) {
#pragma unroll
        for (int r = 0; r < 16; ++r) {
            int h = 32 * rt + (r & 3) + 8 * (r >> 2) + 4 * hi;
            vb[h * 136 + 32 * w + c31] = (short)bfbits(cv[rt][r]);
        }
    }
    __syncthreads();
    {
        int row = tid >> 1, seg = tid & 1;
        const short8* cp = (const short8*)&cb[row * 136 + seg * 64];
        unsigned short* dst = (seg == 0 ? qo : ko) + (t0 + row) * 64;
#pragma unroll
        for (int i = 0; i < 8; ++i) ((short8*)dst)[i] = cp[i];
    }
#pragma unroll
    for (int i = 0; i < 4; ++i) {
        int slot = tid + 256 * i;
        int h = slot >> 4, tc = slot & 15;
        short8 vv = *(const short8*)&vb[h * 136 + 8 * tc];
        *(short8*)(vto + ((long)b * 64 + h) * 4096 + tl0 + 8 * tc) = vv;
    }
}

// ---------------- Kernel 2: MFMA flash attention (R14 compute, 2-buffer R5 sync) ----------------
// 256 thr = 4 waves x 32 q-rows, runtime chunk CT=1<<sh. 2-buffer __syncthreads
// pipeline (R5-proven) with 32 KB LDS -> 5 blocks/CU LDS cap; CT=8 grid 1152
// demands 4.5/CU -> residency ~4.2 blocks (vs R14's 3-buffer 48KB cap of 3).
// All compute/decode/partial paths byte-identical to R14 (passed).
__global__ __launch_bounds__(256, 4) void attn_mfma(
    const unsigned short* __restrict__ qg,
    const unsigned short* __restrict__ kg,
    const unsigned short* __restrict__ vtg,
    unsigned short* __restrict__ Opart,
    float2* __restrict__ ml,
    float* __restrict__ outg,
    int sh, int CPB)
{
    __shared__ short kls[2][4096];
    __shared__ short vls[2][4096];

    const int CT = 1 << sh;
    const int tid = threadIdx.x;
    const int l = tid & 63, w = tid >> 6;     // w in {0..3}
    const int q = l & 31, hi = l >> 5;
    const int qs7 = q & 7;

    const int bid = blockIdx.x;
    const int b = bid & 7;
    const int j = bid >> 3;
    int qt = 0, ci = 0;
    {
        int acc = 0;
        for (int qq = 31; qq >= 0; --qq) {       // descending size (LPT)
            int nc = (2 * qq + 1 + CT) >> sh;    // ceil((2qq+2)/CT)
            if (j < acc + nc) { qt = qq; ci = j - acc; break; }
            acc += nc;
        }
    }
    const int nch = (2 * qt + 1 + CT) >> sh;
    int ntile = 2 * qt + 2 - CT * ci;
    if (ntile > CT) ntile = CT;
    const int c0 = (ci * CT) << 6;

    const int q0w = qt * 128 + 32 * w;
    const int qr = q0w + q;
    const int lastg = (q0w + 31) >> 6;         // wave's diagonal KV tile (global idx)

    const unsigned short* qb = qg + ((long)b * TT + qr) * HD;
    short8 qf[4];
#pragma unroll
    for (int ki = 0; ki < 4; ++ki) qf[ki] = *(const short8*)(qb + 16 * ki + 8 * hi);

    int ofs[2][4];
#pragma unroll
    for (int a = 0; a < 2; ++a)
#pragma unroll
        for (int i2 = 0; i2 < 4; ++i2)
            ofs[a][i2] = (32 * a + q) * 128 + 16 * ((2 * i2 + hi) ^ qs7);

    f32x16 oacc[2] = {};
    float m = -INFINITY, lsum = 0.f;           // lsum: own-half partial

    const unsigned short* kbase = kg + (long)b * TT * HD;
    const unsigned short* vbase = vtg + (long)b * HD * TT;

    const int r8 = l >> 3;
    const int blsw = (l & 7) ^ r8;
    const long koff0 = (long)(8 * w + r8) * HD + 8 * blsw;
    const long voff0 = (long)(8 * w + r8) * TT + 8 * blsw;

#define STAGE(buf_, s_) do {                                                            \
    _Pragma("unroll")                                                                   \
    for (int c_ = 0; c_ < 2; ++c_) {                                                    \
        const unsigned short* kp_ = kbase + (long)(s_) * HD + koff0 + (long)c_ * 32 * HD; \
        const unsigned short* vp_ = vbase + (s_) + voff0 + (long)c_ * 32 * TT;          \
        short* kd_ = &kls[buf_][2048 * c_ + 512 * w];                                   \
        short* vd_ = &vls[buf_][2048 * c_ + 512 * w];                                   \
        __builtin_amdgcn_global_load_lds((const __attribute__((address_space(1))) void*)kp_, \
                                         (__attribute__((address_space(3))) void*)kd_, 16, 0, 0); \
        __builtin_amdgcn_global_load_lds((const __attribute__((address_space(1))) void*)vp_, \
                                         (__attribute__((address_space(3))) void*)vd_, 16, 0, 0); \
    }                                                                                   \
} while (0)

    STAGE(0, c0);

    int cur = 0;
    for (int it = 0; it < ntile; ++it) {
        const int s0 = c0 + (it << 6);
        __syncthreads();                 // vmcnt(0)+barrier: buf[cur] ready, buf[cur^1] free
        if (it + 1 < ntile) STAGE(cur ^ 1, s0 + 64);

        if (s0 <= q0w + 31) {
            const int gti = ci * CT + it;
            const int nkt = (gti == lastg && (w & 1) == 0) ? 1 : 2;
            const short* kb_ = kls[cur];
            const short* vb_ = vls[cur];

            // ---- S^T = K Q^T ----
            f32x16 sacc[2] = {};
            __builtin_amdgcn_s_setprio(1);
#pragma unroll
            for (int kt = 0; kt < 2; ++kt) {
                if (kt < nkt) {
#pragma unroll
                    for (int ki = 0; ki < 4; ++ki) {
                        short8 kf = *(const short8*)((const char*)kb_ + ofs[kt][ki]);
                        sacc[kt] = __builtin_amdgcn_mfma_f32_32x32x16_bf16(kf, qf[ki], sacc[kt], 0, 0, 0);
                    }
                }
            }
            __builtin_amdgcn_s_setprio(0);

            // ---- causal mask (diag tile only) ----
            if (gti == lastg) {
#pragma unroll
                for (int kt = 0; kt < 2; ++kt) {
                    if (kt >= nkt) continue;
#pragma unroll
                    for (int r = 0; r < 16; ++r) {
                        int kkg = s0 + 32 * kt + (r & 3) + 8 * (r >> 2) + 4 * hi;
                        if (kkg > qr) sacc[kt][r] = -INFINITY;
                    }
                }
            }

            // ---- lane-local tree max; rescale only beyond threshold (T13) ----
            float t8[8];
#pragma unroll
            for (int r = 0; r < 8; ++r) {
                float a = fmaxf(sacc[0][r], sacc[0][r + 8]);
                if (nkt == 2) a = fmaxf(a, fmaxf(sacc[1][r], sacc[1][r + 8]));
                t8[r] = a;
            }
            float pmax = fmaxf(fmaxf(fmaxf(t8[0], t8[1]), fmaxf(t8[2], t8[3])),
                               fmaxf(fmaxf(t8[4], t8[5]), fmaxf(t8[6], t8[7])));
            if (__any(pmax > m + 11.0f)) {     // rare in steady state
                pmax = fmaxf(pmax, __shfl_xor(pmax, 32, 64));
                float mn = fmaxf(m, pmax);
                float fac = fexp2(m - mn);
                lsum *= fac;
                oacc[0] *= fac;
                oacc[1] *= fac;
                m = mn;
            }

            // ---- P = exp2(S - m) via raw v_exp; pack via v_cvt_pk ----
            float rsum = 0.f;
            unsigned ulo[8], uhi[8];
#pragma unroll
            for (int kt = 0; kt < 2; ++kt) {
#pragma unroll
                for (int jj = 0; jj < 4; ++jj) {
                    if (kt < nkt) {
                        float p0 = fexp2(sacc[kt][4 * jj + 0] - m);
                        float p1 = fexp2(sacc[kt][4 * jj + 1] - m);
                        float p2 = fexp2(sacc[kt][4 * jj + 2] - m);
                        float p3 = fexp2(sacc[kt][4 * jj + 3] - m);
                        rsum += (p0 + p1) + (p2 + p3);
                        ulo[4 * kt + jj] = pack_bf2(p0, p1);
                        uhi[4 * kt + jj] = pack_bf2(p2, p3);
                    } else {
                        ulo[4 * kt + jj] = 0;
                        uhi[4 * kt + jj] = 0;
                    }
                }
            }
            lsum += rsum;                      // per-half; combined in epilogue

            // ---- O^T += V^T P (P -> A-frag via permlane32_swap, distinct ops) ----
            const int nks = 2 * nkt;
#pragma unroll
            for (int ks = 0; ks < 4; ++ks) {
                if (ks >= nks) continue;
                uint2v rlo = __builtin_amdgcn_permlane32_swap(ulo[2 * ks], ulo[2 * ks + 1], false, false);
                uint2v rhi = __builtin_amdgcn_permlane32_swap(uhi[2 * ks], uhi[2 * ks + 1], false, false);
                uint4v paw;
                paw[0] = rlo[0]; paw[1] = rhi[0]; paw[2] = rlo[1]; paw[3] = rhi[1];
                short8 pa = __builtin_bit_cast(short8, paw);
                __builtin_amdgcn_s_setprio(1);
#pragma unroll
                for (int dt = 0; dt < 2; ++dt) {
                    short8 vf = *(const short8*)((const char*)vb_ + ofs[dt][ks]);
                    oacc[dt] = __builtin_amdgcn_mfma_f32_32x32x16_bf16(vf, pa, oacc[dt], 0, 0, 0);
                }
                __builtin_amdgcn_s_setprio(0);
            }
        }
        cur ^= 1;
    }
#undef STAGE

    lsum += __shfl_xor(lsum, 32, 64);          // combine per-half sums once

    const int lr = 32 * w + q;
    if (nch == 1) {
        const float inv = 1.f / lsum;
        float* op = outg + ((long)b * TT + qr) * HD;
#pragma unroll
        for (int dt = 0; dt < 2; ++dt) {
#pragma unroll
            for (int jj = 0; jj < 4; ++jj) {
                f32x4 o4;
                o4[0] = oacc[dt][4 * jj + 0] * inv;
                o4[1] = oacc[dt][4 * jj + 1] * inv;
                o4[2] = oacc[dt][4 * jj + 2] * inv;
                o4[3] = oacc[dt][4 * jj + 3] * inv;
                *(f32x4*)(op + 32 * dt + 8 * jj + 4 * hi) = o4;
            }
        }
    } else {
        const float inv = lsum > 0.f ? 1.f / lsum : 0.f;
        unsigned short* po = Opart + ((long)(b * CPB + j) * 128 + lr) * 64;
#pragma unroll
        for (int dt = 0; dt < 2; ++dt) {
#pragma unroll
            for (int jj = 0; jj < 4; ++jj) {
                uint2v u;
                u[0] = pack_bf2(oacc[dt][4 * jj + 0] * inv, oacc[dt][4 * jj + 1] * inv);
                u[1] = pack_bf2(oacc[dt][4 * jj + 2] * inv, oacc[dt][4 * jj + 3] * inv);
                *(uint2v*)(po + 32 * dt + 8 * jj + 4 * hi) = u;
            }
        }
        ml[(long)(b * CPB + j) * 128 + lr] = make_float2(m, lsum);
    }
}

// ---------------- Kernel 3: combine partials (runtime chunking; exp2 domain) ----------------
__global__ __launch_bounds__(256) void combine(
    const unsigned short* __restrict__ Opart,
    const float2* __restrict__ ml,
    float* __restrict__ outg,
    int sh, int qtmin, int CPB)
{
    const int CT = 1 << sh;
    const int bid = blockIdx.x;
    const int b = bid & 7, qt = qtmin + (bid >> 3);
    const int nc = (2 * qt + 1 + CT) >> sh;    // 2..8
    int jb = 0;
    for (int qq = 31; qq > qt; --qq) jb += (2 * qq + 1 + CT) >> sh;

    const int tid = threadIdx.x;
    const int row = tid >> 1, dh = (tid & 1) * 32;
    const long base = (long)(b * CPB + jb) * 128 + row;

    float mv[8], lv[8], M = -INFINITY;
#pragma unroll
    for (int c = 0; c < 8; ++c) {
        mv[c] = -INFINITY; lv[c] = 0.f;
        if (c < nc) {
            float2 t = ml[base + (long)c * 128];
            mv[c] = t.x; lv[c] = t.y;
            M = fmaxf(M, mv[c]);
        }
    }
    float L = 0.f, wt[8];
#pragma unroll
    for (int c = 0; c < 8; ++c) {
        wt[c] = (c < nc) ? lv[c] * fexp2(mv[c] - M) : 0.f;
        L += wt[c];
    }
    float acc[32];
#pragma unroll
    for (int i = 0; i < 32; ++i) acc[i] = 0.f;
#pragma unroll
    for (int c = 0; c < 8; ++c) {
        if (c < nc && wt[c] > 0.f) {
            const short8* op = (const short8*)(Opart + (base + (long)c * 128) * 64 + dh);
#pragma unroll
            for (int i = 0; i < 4; ++i) {
                short8 v = op[i];
#pragma unroll
                for (int e = 0; e < 8; ++e)
                    acc[8 * i + e] += wt[c] * bf2f((unsigned short)v[e]);
            }
        }
    }
    const float invL = 1.f / L;
    float* dst = outg + ((long)b * TT + qt * 128 + row) * HD + dh;
#pragma unroll
    for (int i = 0; i < 8; ++i) {
        f32x4 o;
        o[0] = acc[4 * i + 0] * invL; o[1] = acc[4 * i + 1] * invL;
        o[2] = acc[4 * i + 2] * invL; o[3] = acc[4 * i + 3] * invL;
        *(f32x4*)(dst + 4 * i) = o;
    }
}

extern "C" void kernel_launch(void* const* d_in, const int* in_sizes, int n_in,
                              void* d_out, int out_size, void* d_ws, size_t ws_size,
                              hipStream_t stream) {
    const float* x  = (const float*)d_in[0];
    const float* Wk = (const float*)d_in[1];
    const float* Wq = (const float*)d_in[2];
    const float* Wv = (const float*)d_in[3];
    float* out = (float*)d_out;

    const long N = (long)BB * TT * HD;
    unsigned short* q16 = (unsigned short*)d_ws;        // 4 MiB
    unsigned short* k16 = q16 + N;                      // 4 MiB
    unsigned short* vt16 = k16 + N;                     // 4 MiB (V^T [b][d][t])
    const size_t qkv_bytes = 12582912;

    // chunk-size selection: CT=8 iff partials fit the workspace (R14-proven)
    int sh, CPB;
    {
        const size_t need8 = qkv_bytes + (size_t)144 * 8 * 128 * 64 * 2
                                       + (size_t)144 * 8 * 128 * 8;   // 32,636,928
        if (ws_size >= need8) { sh = 3; CPB = 144; }
        else                  { sh = 4; CPB = 80;  }
    }
    unsigned short* Opart = (unsigned short*)((char*)d_ws + qkv_bytes);
    float2* mlp = (float2*)((char*)d_ws + qkv_bytes + (size_t)CPB * 8 * 128 * 64 * 2);
    const int qtmin = 1 << (sh - 1);                    // first qt needing combine

    qkv_proj_mfma<<<BB * TT / 128, 256, 0, stream>>>(x, Wk, Wq, Wv, q16, k16, vt16);
    attn_mfma<<<8 * CPB, 256, 0, stream>>>(q16, k16, vt16, Opart, mlp, out, sh, CPB);
    combine<<<8 * (32 - qtmin), 256, 0, stream>>>(Opart, mlp, out, sh, qtmin, CPB);
}